// Round 11
// baseline (1634.097 us; speedup 1.0000x reference)
//
#include <hip/hip_runtime.h>
#include <hip/hip_bf16.h>

// Problem constants (fixed by setup_inputs)
#define H    300
#define KP   320            // K padded to multiple of 32
#define BM   2048           // num molecules
#define SEG  48
#define NTOK (BM*SEG)       // 98304
#define G    900            // 3*H
#define GP   912            // hp width: 57*16
#define NT   57             // GP/16
#define GW   1024           // wih row-pad: 8*128 (B-operand tiles)
#define XPW  912            // xp row stride (cols >= 900 never read; 912 keeps 4B align)
#define MOLW 16             // molecules per recurrent workgroup
#define WGT  1024           // gru workgroup threads (16 waves -> 4 waves/SIMD, 1 WG/CU)
#define NPAIR (MOLW*150)    // bf16-pairs of gate state per wg = 2400
#define PIT  3              // pointwise iters: ceil(NPAIR/WGT)
#define BKX  64             // xp_gemm K-step

typedef __attribute__((ext_vector_type(8))) short short8;
typedef __attribute__((ext_vector_type(4))) float f32x4;

__device__ __forceinline__ float lo16(unsigned u) { return __uint_as_float(u << 16); }
__device__ __forceinline__ float hi16(unsigned u) { return __uint_as_float(u & 0xffff0000u); }
__device__ __forceinline__ unsigned short bfb(float f) {
    __hip_bfloat16 b = __float2bfloat16(f);
    return *(unsigned short*)&b;
}
__device__ __forceinline__ void gload16(const void* g, void* l) {
    __builtin_amdgcn_global_load_lds((const __attribute__((address_space(1))) unsigned*)g,
                                     (__attribute__((address_space(3))) unsigned*)l, 16, 0, 0);
}

// ---------------- prep: weights -> padded bf16, biases -> padded f32 ----------------
__global__ void prep_weights(const float* wih_f, const float* whh_f, const float* bih_f,
                             const float* wih_b, const float* whh_b, const float* bih_b,
                             __hip_bfloat16* wih, __hip_bfloat16* whh, float* bih) {
    int idx = blockIdx.x * 256 + threadIdx.x;
    const int wih_n = 2 * GW * KP;
    const int whh_n = 2 * GP * KP;
    if (idx < wih_n) {
        int d = idx / (GW * KP);
        int r = (idx / KP) % GW;
        int k = idx % KP;
        const float* src = d ? wih_b : wih_f;
        float v = (r < G && k < H) ? src[r * H + k] : 0.f;
        wih[idx] = __float2bfloat16(v);
        return;
    }
    idx -= wih_n;
    if (idx < whh_n) {
        int d = idx / (GP * KP);
        int r = (idx / KP) % GP;
        int k = idx % KP;
        const float* src = d ? whh_b : whh_f;
        float v = (r < G && k < H) ? src[r * H + k] : 0.f;
        whh[idx] = __float2bfloat16(v);
        return;
    }
    idx -= whh_n;
    if (idx < 2 * GW) {
        int d = idx / GW;
        int r = idx % GW;
        const float* src = d ? bih_b : bih_f;
        bih[idx] = (r < G) ? src[r] : 0.f;
    }
}

// ---------------- prep: message = bf16(relu(x + bias)), K-padded ----------------
__global__ void prep_msg(const float* x, const float* bias, __hip_bfloat16* msg) {
    int idx = blockIdx.x * 256 + threadIdx.x;      // over NTOK*KP
    if (idx >= NTOK * KP) return;
    int i = idx / KP, k = idx % KP;
    float v = 0.f;
    if (k < H) {
        v = x[i * H + k] + bias[k];
        v = v > 0.f ? v : 0.f;
    }
    msg[idx] = __float2bfloat16(v);
}

// ---------------- prep: h0 = segment_max(x) ----------------
__global__ void h0_kernel(const float* x, float* h0) {
    int m = blockIdx.x;
    for (int c = threadIdx.x; c < H; c += blockDim.x) {
        const float* base = x + (long long)m * SEG * H + c;
        float v = -INFINITY;
        for (int t = 0; t < SEG; t++) v = fmaxf(v, base[t * H]);
        h0[m * H + c] = v;
    }
}

// ---------------- xp = msg @ w_ih^T + b_ih  (m97-style: global_load_lds staging, 128x128 tile) ----------------
// Measured: non-gru total 546-550 us with this version.
__global__ __launch_bounds__(256) void xp_gemm(const __hip_bfloat16* msg, const __hip_bfloat16* wih,
                                               const float* bih, __hip_bfloat16* xp) {
    int d = blockIdx.z;
    const __hip_bfloat16* A  = msg;
    const __hip_bfloat16* Bw = wih + d * GW * KP;
    const float* bi = bih + d * GW;
    __hip_bfloat16* out = xp + (long long)d * NTOK * XPW;

    __shared__ __hip_bfloat16 sA[128 * BKX];   // 16 KB
    __shared__ __hip_bfloat16 sB[128 * BKX];   // 16 KB
    const short* sAs = (const short*)sA;
    const short* sBs = (const short*)sB;

    int tid = threadIdx.x;
    int lane = tid & 63, wid = tid >> 6;
    int l15 = lane & 15, quad = lane >> 4;
    int mblk = blockIdx.x * 128, nblk = blockIdx.y * 128;
    int mbase = (wid >> 1) * 64, nbase = (wid & 1) * 64;

    int srow = wid * 32 + (lane >> 3);          // local row at j=0 (rows += 8 per j)
    int scc  = (lane & 7) ^ (srow & 7);         // swizzled source chunk-in-row
    const short* gA0 = (const short*)A  + (long long)(mblk + srow) * KP + scc * 8;
    const short* gB0 = (const short*)Bw + (long long)(nblk + srow) * KP + scc * 8;
    int xsw = (l15 & 7) << 3;                   // read-side XOR (shorts)

    f32x4 acc[4][4] = {};
    for (int kc = 0; kc < KP / BKX; kc++) {
#pragma unroll
        for (int j = 0; j < 4; j++)
            gload16(gA0 + (long long)j * 8 * KP + kc * BKX, (char*)sA + (wid * 4 + j) * 1024);
#pragma unroll
        for (int j = 0; j < 4; j++)
            gload16(gB0 + (long long)j * 8 * KP + kc * BKX, (char*)sB + (wid * 4 + j) * 1024);
        __syncthreads();   // compiler drains vmcnt before s_barrier -> LDS tiles ready

        short8 af[4][2], bf[4][2];
#pragma unroll
        for (int i = 0; i < 4; i++)
#pragma unroll
            for (int kh = 0; kh < 2; kh++)
                af[i][kh] = *(const short8*)(sAs + (mbase + i * 16 + l15) * BKX + ((kh * 32 + quad * 8) ^ xsw));
#pragma unroll
        for (int j = 0; j < 4; j++)
#pragma unroll
            for (int kh = 0; kh < 2; kh++)
                bf[j][kh] = *(const short8*)(sBs + (nbase + j * 16 + l15) * BKX + ((kh * 32 + quad * 8) ^ xsw));
#pragma unroll
        for (int i = 0; i < 4; i++)
#pragma unroll
            for (int j = 0; j < 4; j++) {
                acc[i][j] = __builtin_amdgcn_mfma_f32_16x16x32_bf16(af[i][0], bf[j][0], acc[i][j], 0, 0, 0);
                acc[i][j] = __builtin_amdgcn_mfma_f32_16x16x32_bf16(af[i][1], bf[j][1], acc[i][j], 0, 0, 0);
            }
        __syncthreads();   // before next kc overwrites LDS
    }

#pragma unroll
    for (int i = 0; i < 4; i++)
#pragma unroll
        for (int j = 0; j < 4; j++) {
            int col = nblk + nbase + j * 16 + l15;
            if (col < XPW) {
                float bv = bi[col];
#pragma unroll
                for (int r = 0; r < 4; r++) {
                    int row = mblk + mbase + i * 16 + quad * 4 + r;
                    out[(long long)row * XPW + col] = __float2bfloat16(acc[i][j][r] + bv);
                }
            }
        }
}

// asm b-fragment load: 16B per lane, immediate offset folds kk (volatile: issue order pinned)
#define GLD(dst, base, imm) \
    asm volatile("global_load_dwordx4 %0, %1, off offset:%2" : "=v"(dst) : "v"(base), "n"(imm))

// ---------------- persistent bidirectional GRU over 48 steps ----------------
// R10 base (957 us, FETCH 0.18 GB, Occ 48%) + THIS ROUND: kk-outer GEMM with inline-asm
// b-loads and counted s_waitcnt vmcnt(4) (compiler cannot collapse the pipeline). afA drops
// from 10 hoisted fragments (40 VGPRs -> MLP~1 at the 64-VGPR cap) to 1-2 live, freeing
// registers for 8 in-flight b-fragments (2 kk-slices x 4 tiles).
__global__ __launch_bounds__(WGT, 4) void gru_kernel(const __hip_bfloat16* whh_all, const float* bhh_f,
                                                     const float* bhh_b, const __hip_bfloat16* xp,
                                                     const float* h0, float* out) {
    int grp = blockIdx.x;      // molecule group, 0..127
    int d   = blockIdx.y;      // direction
    const short* Ws = (const short*)(whh_all + d * GP * KP);
    const float* bhh = d ? bhh_b : bhh_f;
    const __hip_bfloat16* xpd = xp + (long long)d * NTOK * XPW;

    int tid = threadIdx.x;
    int lane = tid & 63, wid = tid >> 6;           // wid 0..15
    int l15 = lane & 15, quad = lane >> 4;

    __shared__ __hip_bfloat16 hB[MOLW * 328];      // 10,496 B  bf16 h (A-operand), stride 328
    __shared__ __hip_bfloat16 hp[MOLW * GP];       // 29,184 B  recurrent projections (+b_hh)
    const short* hBs = (const short*)hB;

    int mol0 = grp * MOLW;

    // ---- zero hB (incl. K-pad cols 300..327) ----
    for (int e = tid; e < MOLW * 328; e += WGT) hB[e] = __float2bfloat16(0.f);

    // ---- per-wave tiles nt = wid + 16k (k<4); k=3 invalid for wid>=9: clamp to tile wid
    //      (duplicate loads/MFMA, store guarded) for a uniform 4-tile asm pipeline ----
    const short* bp4[4];
    float bvw[4];
#pragma unroll
    for (int k = 0; k < 4; k++) {
        int nt = wid + 16 * k;
        int ntc = (nt < NT) ? nt : wid;
        bp4[k] = Ws + (ntc * 16 + l15) * KP + quad * 8;
        int gc = nt * 16 + l15;
        bvw[k] = (nt < NT && gc < G) ? bhh[gc] : 0.f;
    }
    __syncthreads();   // hB zeros visible before pair-writes below

    // ---- init h state: registers (gate-thread ownership) + hB bf16 copy ----
    float hv0[PIT], hv1[PIT];
#pragma unroll
    for (int i = 0; i < PIT; i++) {
        int e2 = tid + i * WGT;
        if (e2 < NPAIR) {
            int m = e2 / 150, c = 2 * (e2 % 150);
            float2 hh = *(const float2*)(h0 + (size_t)(mol0 + m) * H + c);
            hv0[i] = hh.x; hv1[i] = hh.y;
            unsigned pack = ((unsigned)bfb(hh.y) << 16) | bfb(hh.x);
            *(unsigned*)(&hB[m * 328 + c]) = pack;
        }
    }
    __syncthreads();

    for (int t = 0; t < SEG; t++) {
        int tt = d ? (SEG - 1 - t) : t;

        // ---- issue xp prefetch for this step (oldest in vmcnt FIFO; drained by first vmcnt(4)) ----
        unsigned pr[PIT], pz[PIT], pn[PIT];
#pragma unroll
        for (int i = 0; i < PIT; i++) {
            int e2 = tid + i * WGT;
            if (e2 < NPAIR) {
                int m = e2 / 150, c = 2 * (e2 % 150);
                const __hip_bfloat16* xrow = xpd + ((long long)(mol0 + m) * SEG + tt) * XPW;
                pr[i] = *(const unsigned*)(xrow + c);
                pz[i] = *(const unsigned*)(xrow + c + 300);
                pn[i] = *(const unsigned*)(xrow + c + 600);
            }
        }
        __builtin_amdgcn_sched_barrier(0);   // pin xp issue above the asm b-loads

        // ---- GEMM: hp = h @ w_hh^T + b_hh  (kk-outer, asm 2-deep b pipeline, vmcnt(4)) ----
        f32x4 acc0 = {}, acc1 = {}, acc2 = {}, acc3 = {};
        short8 bc0, bc1, bc2, bc3, bn0, bn1, bn2, bn3;
        GLD(bc0, bp4[0], 0); GLD(bc1, bp4[1], 0); GLD(bc2, bp4[2], 0); GLD(bc3, bp4[3], 0);
        short8 ac = *(const short8*)(hBs + l15 * 328 + quad * 8);
#pragma unroll
        for (int kk = 0; kk < 10; kk++) {
            if (kk < 9) {
                GLD(bn0, bp4[0], (kk + 1) * 64); GLD(bn1, bp4[1], (kk + 1) * 64);
                GLD(bn2, bp4[2], (kk + 1) * 64); GLD(bn3, bp4[3], (kk + 1) * 64);
                asm volatile("s_waitcnt vmcnt(4)" ::: "memory");   // bc ready; bn in flight
            } else {
                asm volatile("s_waitcnt vmcnt(0)" ::: "memory");
            }
            __builtin_amdgcn_sched_barrier(0);                     // rule #18: no MFMA hoist
            short8 an;
            if (kk < 9) an = *(const short8*)(hBs + l15 * 328 + (kk + 1) * 32 + quad * 8);
            acc0 = __builtin_amdgcn_mfma_f32_16x16x32_bf16(ac, bc0, acc0, 0, 0, 0);
            acc1 = __builtin_amdgcn_mfma_f32_16x16x32_bf16(ac, bc1, acc1, 0, 0, 0);
            acc2 = __builtin_amdgcn_mfma_f32_16x16x32_bf16(ac, bc2, acc2, 0, 0, 0);
            acc3 = __builtin_amdgcn_mfma_f32_16x16x32_bf16(ac, bc3, acc3, 0, 0, 0);
            bc0 = bn0; bc1 = bn1; bc2 = bn2; bc3 = bn3; ac = an;
        }

        // ---- hp stores (guarded; duplicate 4th tile skipped) ----
        {
            f32x4 accs[4] = {acc0, acc1, acc2, acc3};
#pragma unroll
            for (int k = 0; k < 4; k++) {
                int nt = wid + 16 * k;
                if (nt < NT) {
                    int gcol = nt * 16 + l15;
                    float bv = bvw[k];
#pragma unroll
                    for (int r = 0; r < 4; r++)
                        hp[(quad * 4 + r) * GP + gcol] = __float2bfloat16(accs[k][r] + bv);
                }
            }
        }
        __syncthreads();

        // ---- pointwise GRU gates (fp32, 2 elems/thread/iter) ----
#pragma unroll
        for (int i = 0; i < PIT; i++) {
            int e2 = tid + i * WGT;
            if (e2 < NPAIR) {
                int m = e2 / 150, c = 2 * (e2 % 150);
                unsigned hr2 = *(const unsigned*)(&hp[m * GP + c]);
                unsigned hz2 = *(const unsigned*)(&hp[m * GP + c + 300]);
                unsigned hn2 = *(const unsigned*)(&hp[m * GP + c + 600]);

                float xr0 = lo16(pr[i]), xr1 = hi16(pr[i]);
                float xz0 = lo16(pz[i]), xz1 = hi16(pz[i]);
                float xn0 = lo16(pn[i]), xn1 = hi16(pn[i]);
                float hr0 = lo16(hr2),  hr1 = hi16(hr2);
                float hz0 = lo16(hz2),  hz1 = hi16(hz2);
                float hn0 = lo16(hn2),  hn1 = hi16(hn2);

                float rg0 = 1.f / (1.f + __expf(-(xr0 + hr0)));
                float rg1 = 1.f / (1.f + __expf(-(xr1 + hr1)));
                float zg0 = 1.f / (1.f + __expf(-(xz0 + hz0)));
                float zg1 = 1.f / (1.f + __expf(-(xz1 + hz1)));
                float ni0 = xn0 + rg0 * hn0;
                float ni1 = xn1 + rg1 * hn1;
                float ng0 = 1.f - 2.f / (__expf(2.f * ni0) + 1.f);
                float ng1 = 1.f - 2.f / (__expf(2.f * ni1) + 1.f);
                float h0n = (1.f - zg0) * ng0 + zg0 * hv0[i];
                float h1n = (1.f - zg1) * ng1 + zg1 * hv1[i];
                hv0[i] = h0n; hv1[i] = h1n;

                unsigned pack = ((unsigned)bfb(h1n) << 16) | bfb(h0n);
                *(unsigned*)(&hB[m * 328 + c]) = pack;

                long long tok = (long long)(mol0 + m) * SEG + tt;
                *(float2*)(out + tok * 600 + d * 300 + c) = make_float2(h0n, h1n);
            }
        }
        __syncthreads();
    }
}

extern "C" void kernel_launch(void* const* d_in, const int* in_sizes, int n_in,
                              void* d_out, int out_size, void* d_ws, size_t ws_size,
                              hipStream_t stream) {
    const float* x     = (const float*)d_in[0];
    const float* bias  = (const float*)d_in[4];
    const float* wih_f = (const float*)d_in[5];
    const float* whh_f = (const float*)d_in[6];
    const float* bih_f = (const float*)d_in[7];
    const float* bhh_f = (const float*)d_in[8];
    const float* wih_b = (const float*)d_in[9];
    const float* whh_b = (const float*)d_in[10];
    const float* bih_b = (const float*)d_in[11];
    const float* bhh_b = (const float*)d_in[12];
    float* out = (float*)d_out;

    // Workspace layout (total 426,471,424 B ~= 406.7 MiB)
    char* ws = (char*)d_ws;
    __hip_bfloat16* msg = (__hip_bfloat16*)(ws);                    //  62,914,560 B
    __hip_bfloat16* wih = (__hip_bfloat16*)(ws + 62914560LL);       //   1,310,720 B
    __hip_bfloat16* whh = (__hip_bfloat16*)(ws + 64225280LL);       //   1,167,360 B
    float*          bih = (float*)         (ws + 65392640LL);       //       8,192 B
    float*          h0  = (float*)         (ws + 65400832LL);       //   2,457,600 B
    __hip_bfloat16* xp  = (__hip_bfloat16*)(ws + 67858432LL);       // 358,612,992 B

    hipLaunchKernelGGL(prep_weights, dim3((2*GW*KP + 2*GP*KP + 2*GW + 255) / 256), dim3(256), 0, stream,
                       wih_f, whh_f, bih_f, wih_b, whh_b, bih_b, wih, whh, bih);
    hipLaunchKernelGGL(prep_msg, dim3((NTOK * KP + 255) / 256), dim3(256), 0, stream, x, bias, msg);
    hipLaunchKernelGGL(h0_kernel, dim3(BM), dim3(256), 0, stream, x, h0);
    hipLaunchKernelGGL(xp_gemm, dim3(NTOK / 128, GW / 128, 2), dim3(256), 0, stream, msg, wih, bih, xp);
    hipLaunchKernelGGL(gru_kernel, dim3(BM / MOLW, 2), dim3(WGT), 0, stream, whh, bhh_f, bhh_b, xp, h0, out);
}